// Round 6
// baseline (916.898 us; speedup 1.0000x reference)
//
#include <hip/hip_runtime.h>
#include <hip/hip_bf16.h>
#include <cstdint>

#define D 128
#define NEG_SLOPE 0.2f
#define LN_EPS 1e-5f
#define SM_EPS 1e-16f

// ---------------- CSR build ----------------

__global__ void deg_init(int* __restrict__ deg, int n) {
    int v = blockIdx.x * blockDim.x + threadIdx.x;
    if (v < n) deg[v] = 1;  // self-loop
}

__global__ void hist_dst(const int* __restrict__ dst, int E, int* __restrict__ deg) {
    int e = blockIdx.x * blockDim.x + threadIdx.x;
    if (e < E) atomicAdd(&deg[dst[e]], 1);
}

__global__ void scanA(const int* __restrict__ deg, int n,
                      int* __restrict__ excl, int* __restrict__ bsums) {
    __shared__ int s[256];
    int t = threadIdx.x;
    int v = blockIdx.x * 256 + t;
    int d = (v < n) ? deg[v] : 0;
    s[t] = d;
    __syncthreads();
    for (int off = 1; off < 256; off <<= 1) {
        int tv = (t >= off) ? s[t - off] : 0;
        __syncthreads();
        s[t] += tv;
        __syncthreads();
    }
    if (v < n) excl[v] = s[t] - d;
    if (t == 255) bsums[blockIdx.x] = s[255];
}

__global__ void scanB(int* __restrict__ bsums, int nb) {
    if (threadIdx.x == 0 && blockIdx.x == 0) {
        int run = 0;
        for (int i = 0; i < nb; ++i) {
            int t = bsums[i];
            bsums[i] = run;
            run += t;
        }
    }
}

__global__ void scanC(int* __restrict__ rowptr, const int* __restrict__ bsums,
                      int n, int total) {
    int v = blockIdx.x * blockDim.x + threadIdx.x;
    if (v < n) rowptr[v] += bsums[v >> 8];
    if (v == 0) rowptr[n] = total;
}

__global__ void fill_csr(const int* __restrict__ src, const int* __restrict__ dst,
                         int E, int n, const int* __restrict__ rowptr,
                         int* __restrict__ cursor, int* __restrict__ col) {
    int t = blockIdx.x * blockDim.x + threadIdx.x;
    int tot = E + n;
    if (t >= tot) return;
    int s, d;
    if (t < E) { s = src[t]; d = dst[t]; }
    else       { s = t - E; d = s; }       // self loop
    int p = rowptr[d] + atomicAdd(&cursor[d], 1);
    col[p] = s;
}

// ---------------- GEMM h = x@W with alpha epilogue ----------------
// block = 256 threads, 64-row tile, full 128-col width.
// thread t: col-group m = t&31 owns cols 4m..4m+3; row-group g = t>>5 owns rows 8g..8g+7.

__global__ __launch_bounds__(256) void gemm_alpha(
        const float* __restrict__ x, const float* __restrict__ W,
        const float* __restrict__ asrc, const float* __restrict__ adst,
        float* __restrict__ h, float* __restrict__ as_, float* __restrict__ ad_, int n) {
    __shared__ float sX[64][D];
    int t = threadIdx.x;
    int row0 = blockIdx.x * 64;

    const float4* xv = (const float4*)x;
    #pragma unroll
    for (int i = 0; i < 8; ++i) {
        int fid = i * 256 + t;          // 0..2047 float4 slots
        int r = fid >> 5;               // 32 float4 per row
        int c4 = fid & 31;
        int gr = row0 + r;
        float4 val = (gr < n) ? xv[(size_t)gr * 32 + c4] : make_float4(0.f, 0.f, 0.f, 0.f);
        ((float4*)&sX[r][0])[c4] = val;
    }
    __syncthreads();

    int g = t >> 5, m = t & 31;
    int rbase = g * 8;
    float4 acc[8];
    #pragma unroll
    for (int r = 0; r < 8; ++r) acc[r] = make_float4(0.f, 0.f, 0.f, 0.f);

    const float4* Wv = (const float4*)W;
    #pragma unroll 4
    for (int k = 0; k < D; ++k) {
        float4 w = Wv[k * 32 + m];
        #pragma unroll
        for (int r = 0; r < 8; ++r) {
            float xval = sX[rbase + r][k];
            acc[r].x += xval * w.x;
            acc[r].y += xval * w.y;
            acc[r].z += xval * w.z;
            acc[r].w += xval * w.w;
        }
    }

    float4 a_s = ((const float4*)asrc)[m];
    float4 a_d = ((const float4*)adst)[m];
    #pragma unroll
    for (int r = 0; r < 8; ++r) {
        int gr = row0 + rbase + r;
        if (gr < n) {
            ((float4*)h)[(size_t)gr * 32 + m] = acc[r];
            float ps = acc[r].x * a_s.x + acc[r].y * a_s.y + acc[r].z * a_s.z + acc[r].w * a_s.w;
            float pd = acc[r].x * a_d.x + acc[r].y * a_d.y + acc[r].z * a_d.z + acc[r].w * a_d.w;
            #pragma unroll
            for (int d = 16; d >= 1; d >>= 1) {
                ps += __shfl_xor(ps, d);
                pd += __shfl_xor(pd, d);
            }
            if (m == 0) { as_[gr] = ps; ad_[gr] = pd; }
        }
    }
}

// ---------------- fused softmax-aggregate + residual + LN + ReLU ----------------
// one 64-lane wave per dst node; lane owns feature elements 2*lane, 2*lane+1.
// NOTE: xout == xin is safe — each wave reads xin only at its own row v
// (residual, epilogue) and writes only row v.

__global__ __launch_bounds__(256) void aggregate(
        const float* __restrict__ xin, const float* __restrict__ h,
        const float* __restrict__ as_, const float* __restrict__ ad_,
        const int* __restrict__ col, const int* __restrict__ rowptr,
        const float* __restrict__ bias, const float* __restrict__ gamma,
        const float* __restrict__ beta, float* __restrict__ xout, int n) {
    int wid = (int)((blockIdx.x * blockDim.x + threadIdx.x) >> 6);
    int lane = threadIdx.x & 63;
    if (wid >= n) return;
    int v = wid;
    int start = rowptr[v], end = rowptr[v + 1];
    float adv = ad_[v];

    // pass 1: segment max (lane-parallel)
    float mval = -1e30f;
    for (int e = start + lane; e < end; e += 64) {
        int s = col[e];
        float a = as_[s] + adv;
        a = (a > 0.f) ? a : NEG_SLOPE * a;
        mval = fmaxf(mval, a);
    }
    #pragma unroll
    for (int d = 32; d >= 1; d >>= 1) mval = fmaxf(mval, __shfl_xor(mval, d));

    // pass 2: chunked — compute weights lane-parallel, redistribute via shfl,
    // accumulate weighted h rows (512B coalesced per edge).
    float sacc = 0.f, a0 = 0.f, a1 = 0.f;
    for (int base = start; base < end; base += 64) {
        int e = base + lane;
        int sl = 0;
        float wl = 0.f;
        if (e < end) {
            sl = col[e];
            float a = as_[sl] + adv;
            a = (a > 0.f) ? a : NEG_SLOPE * a;
            wl = __expf(a - mval);
        }
        sacc += wl;
        int cnt = min(64, end - base);
        for (int i = 0; i < cnt; ++i) {
            float w = __shfl(wl, i);
            int s = __shfl(sl, i);
            const float2 hv = *(const float2*)(h + (size_t)s * D + lane * 2);
            a0 += w * hv.x;
            a1 += w * hv.y;
        }
    }
    #pragma unroll
    for (int d = 32; d >= 1; d >>= 1) sacc += __shfl_xor(sacc, d);
    float inv = 1.f / (sacc + SM_EPS);

    // epilogue: residual + bias + LayerNorm + ReLU
    float2 xr = *(const float2*)(xin + (size_t)v * D + lane * 2);
    float y0 = xr.x + a0 * inv + bias[lane * 2];
    float y1 = xr.y + a1 * inv + bias[lane * 2 + 1];

    float s2 = y0 + y1;
    #pragma unroll
    for (int d = 32; d >= 1; d >>= 1) s2 += __shfl_xor(s2, d);
    float mu = s2 * (1.f / 128.f);
    float d0 = y0 - mu, d1 = y1 - mu;
    float vs = d0 * d0 + d1 * d1;
    #pragma unroll
    for (int d = 32; d >= 1; d >>= 1) vs += __shfl_xor(vs, d);
    float rstd = rsqrtf(vs * (1.f / 128.f) + LN_EPS);

    float o0 = d0 * rstd * gamma[lane * 2] + beta[lane * 2];
    float o1 = d1 * rstd * gamma[lane * 2 + 1] + beta[lane * 2 + 1];
    o0 = fmaxf(o0, 0.f);
    o1 = fmaxf(o1, 0.f);
    *(float2*)(xout + (size_t)v * D + lane * 2) = make_float2(o0, o1);
}

// ---------------- launch ----------------

extern "C" void kernel_launch(void* const* d_in, const int* in_sizes, int n_in,
                              void* d_out, int out_size, void* d_ws, size_t ws_size,
                              hipStream_t stream) {
    const float* x       = (const float*)d_in[0];
    const int*   edge    = (const int*)d_in[1];
    const float* W       = (const float*)d_in[2];
    const float* att_src = (const float*)d_in[3];
    const float* att_dst = (const float*)d_in[4];
    const float* bias    = (const float*)d_in[5];
    const float* gamma   = (const float*)d_in[6];
    const float* beta    = (const float*)d_in[7];
    float* out = (float*)d_out;

    const int N = in_sizes[0] / D;       // 100000
    const int E = in_sizes[1] / 2;       // 1600000
    const int tot = E + N;

    const int* src = edge;
    const int* dst = edge + E;

    // ---- workspace carve (512B-aligned regions) ----
    char* ws = (char*)d_ws;
    size_t off = 0;
    auto carve = [&](size_t bytes) -> char* {
        char* p = ws + off;
        off = (off + bytes + 511) & ~(size_t)511;
        return p;
    };
    int*   rowptr = (int*)carve((size_t)(N + 1) * 4);
    int*   cursor = (int*)carve((size_t)N * 4);        // also deg
    int*   bsums  = (int*)carve(512 * 4);
    int*   col    = (int*)carve((size_t)tot * 4);
    float* h      = (float*)carve((size_t)N * D * 4);
    float* as_    = (float*)carve((size_t)N * 4);
    float* ad_    = (float*)carve((size_t)N * 4);
    float* x1     = (float*)carve((size_t)N * D * 4);
    (void)ws_size;

    const int TPB = 256;
    int nbN  = (N + TPB - 1) / TPB;       // 391
    int nbE  = (E + TPB - 1) / TPB;
    int nbT  = (tot + TPB - 1) / TPB;

    // ---- CSR build (deg in `cursor`) ----
    deg_init<<<nbN, TPB, 0, stream>>>(cursor, N);
    hist_dst<<<nbE, TPB, 0, stream>>>(dst, E, cursor);
    scanA<<<nbN, TPB, 0, stream>>>(cursor, N, rowptr, bsums);
    scanB<<<1, 64, 0, stream>>>(bsums, nbN);
    scanC<<<nbN, TPB, 0, stream>>>(rowptr, bsums, N, tot);
    hipMemsetAsync(cursor, 0, (size_t)N * 4, stream);
    fill_csr<<<nbT, TPB, 0, stream>>>(src, dst, E, N, rowptr, cursor, col);

    // ---- 3 levels (x -> x1 -> x1 -> out; in-place agg is row-exclusive) ----
    int gemmGrid = (N + 63) / 64;         // 1563
    int aggGrid  = (N * 64 + TPB - 1) / TPB;  // wave-per-node: N waves, 4/block

    const float* xin = x;
    float* bufs[3] = { x1, x1, out };
    for (int l = 0; l < 3; ++l) {
        const float* Wl  = W + (size_t)l * D * D;
        const float* asl = att_src + (size_t)l * D;
        const float* adl = att_dst + (size_t)l * D;
        const float* bl  = bias + (size_t)l * D;
        const float* gl  = gamma + (size_t)l * D;
        const float* btl = beta + (size_t)l * D;
        float* xout = bufs[l];

        gemm_alpha<<<gemmGrid, TPB, 0, stream>>>(xin, Wl, asl, adl, h, as_, ad_, N);
        aggregate<<<aggGrid, TPB, 0, stream>>>(xin, h, as_, ad_, col, rowptr,
                                               bl, gl, btl, xout, N);
        xin = xout;
    }
}

// Round 8
// 812.970 us; speedup vs baseline: 1.1278x; 1.1278x over previous
//
#include <hip/hip_runtime.h>
#include <hip/hip_fp16.h>
#include <cstdint>

#define D 128
#define NEG_SLOPE 0.2f
#define LN_EPS 1e-5f
#define SM_EPS 1e-16f

// ---------------- CSR build (real edges only; self-loops handled analytically) ----

__global__ void hist_dst(const int* __restrict__ dst, int E, int* __restrict__ deg) {
    int e = blockIdx.x * blockDim.x + threadIdx.x;
    if (e < E) atomicAdd(&deg[dst[e]], 1);
}

__global__ void scanA(const int* __restrict__ deg, int n,
                      int* __restrict__ excl, int* __restrict__ bsums) {
    __shared__ int s[256];
    int t = threadIdx.x;
    int v = blockIdx.x * 256 + t;
    int d = (v < n) ? deg[v] : 0;
    s[t] = d;
    __syncthreads();
    for (int off = 1; off < 256; off <<= 1) {
        int tv = (t >= off) ? s[t - off] : 0;
        __syncthreads();
        s[t] += tv;
        __syncthreads();
    }
    if (v < n) excl[v] = s[t] - d;
    if (t == 255) bsums[blockIdx.x] = s[255];
}

// parallel exclusive scan of block sums (nb <= 512)
__global__ void scanB(int* __restrict__ bsums, int nb) {
    __shared__ int s[512];
    int t = threadIdx.x;
    int v = (t < nb) ? bsums[t] : 0;
    s[t] = v;
    __syncthreads();
    for (int off = 1; off < 512; off <<= 1) {
        int tv = (t >= off) ? s[t - off] : 0;
        __syncthreads();
        s[t] += tv;
        __syncthreads();
    }
    if (t < nb) bsums[t] = s[t] - v;   // exclusive
}

// rowptr += block offset; also zero cursor for fill_csr
__global__ void scanC(int* __restrict__ rowptr, const int* __restrict__ bsums,
                      int* __restrict__ cursor, int n, int total) {
    int v = blockIdx.x * blockDim.x + threadIdx.x;
    if (v < n) { rowptr[v] += bsums[v >> 8]; cursor[v] = 0; }
    if (v == 0) rowptr[n] = total;
}

__global__ void fill_csr(const int* __restrict__ src, const int* __restrict__ dst,
                         int E, const int* __restrict__ rowptr,
                         int* __restrict__ cursor, int* __restrict__ col) {
    int e = blockIdx.x * blockDim.x + threadIdx.x;
    if (e >= E) return;
    int d = dst[e];
    int p = rowptr[d] + atomicAdd(&cursor[d], 1);
    col[p] = src[e];
}

// ---------------- GEMM h = x@W (h stored fp16) with alpha epilogue ----------------
// block = 256 threads, 64-row tile, full 128-col width.
// thread t: col-group m = t&31 owns cols 4m..4m+3; row-group g = t>>5 owns rows 8g..8g+7.

__global__ __launch_bounds__(256) void gemm_alpha(
        const float* __restrict__ x, const float* __restrict__ W,
        const float* __restrict__ asrc, const float* __restrict__ adst,
        __half* __restrict__ h, float* __restrict__ as_, float* __restrict__ ad_, int n) {
    __shared__ float sX[64][D];
    int t = threadIdx.x;
    int row0 = blockIdx.x * 64;

    const float4* xv = (const float4*)x;
    #pragma unroll
    for (int i = 0; i < 8; ++i) {
        int fid = i * 256 + t;          // 0..2047 float4 slots
        int r = fid >> 5;               // 32 float4 per row
        int c4 = fid & 31;
        int gr = row0 + r;
        float4 val = (gr < n) ? xv[(size_t)gr * 32 + c4] : make_float4(0.f, 0.f, 0.f, 0.f);
        ((float4*)&sX[r][0])[c4] = val;
    }
    __syncthreads();

    int g = t >> 5, m = t & 31;
    int rbase = g * 8;
    float4 acc[8];
    #pragma unroll
    for (int r = 0; r < 8; ++r) acc[r] = make_float4(0.f, 0.f, 0.f, 0.f);

    const float4* Wv = (const float4*)W;
    #pragma unroll 4
    for (int k = 0; k < D; ++k) {
        float4 w = Wv[k * 32 + m];
        #pragma unroll
        for (int r = 0; r < 8; ++r) {
            float xval = sX[rbase + r][k];
            acc[r].x += xval * w.x;
            acc[r].y += xval * w.y;
            acc[r].z += xval * w.z;
            acc[r].w += xval * w.w;
        }
    }

    float4 a_s = ((const float4*)asrc)[m];
    float4 a_d = ((const float4*)adst)[m];
    #pragma unroll
    for (int r = 0; r < 8; ++r) {
        int gr = row0 + rbase + r;
        if (gr < n) {
            union { __half2 h2[2]; float2 f2; } u;
            u.h2[0] = __floats2half2_rn(acc[r].x, acc[r].y);
            u.h2[1] = __floats2half2_rn(acc[r].z, acc[r].w);
            ((float2*)(h + (size_t)gr * D))[m] = u.f2;   // 8B store of 4 halves
            float ps = acc[r].x * a_s.x + acc[r].y * a_s.y + acc[r].z * a_s.z + acc[r].w * a_s.w;
            float pd = acc[r].x * a_d.x + acc[r].y * a_d.y + acc[r].z * a_d.z + acc[r].w * a_d.w;
            #pragma unroll
            for (int d = 16; d >= 1; d >>= 1) {
                ps += __shfl_xor(ps, d);
                pd += __shfl_xor(pd, d);
            }
            if (m == 0) { as_[gr] = ps; ad_[gr] = pd; }
        }
    }
}

// ---------------- fused softmax-aggregate + residual + LN + ReLU ----------------
// one 64-lane wave per dst node; lane owns feature elements 2*lane, 2*lane+1.
// Self-loop handled analytically (not in CSR). xout == xin is safe (row-exclusive).

__global__ __launch_bounds__(256) void aggregate(
        const float* __restrict__ xin, const __half* __restrict__ h,
        const float* __restrict__ as_, const float* __restrict__ ad_,
        const int* __restrict__ col, const int* __restrict__ rowptr,
        const float* __restrict__ bias, const float* __restrict__ gamma,
        const float* __restrict__ beta, float* __restrict__ xout, int n) {
    int wid = (int)((blockIdx.x * blockDim.x + threadIdx.x) >> 6);
    int lane = threadIdx.x & 63;
    if (wid >= n) return;
    int v = wid;
    int start = rowptr[v], end = rowptr[v + 1];
    float adv = ad_[v];
    float asv = as_[v];
    float self_a = asv + adv;
    self_a = (self_a > 0.f) ? self_a : NEG_SLOPE * self_a;

    const __half2* h2 = (const __half2*)h;   // 64 half2 per row

    // pass 1: segment max (lane-parallel), seeded with self-loop logit
    float mval = self_a;
    for (int e = start + lane; e < end; e += 64) {
        int s = col[e];
        float a = as_[s] + adv;
        a = (a > 0.f) ? a : NEG_SLOPE * a;
        mval = fmaxf(mval, a);
    }
    #pragma unroll
    for (int d = 32; d >= 1; d >>= 1) mval = fmaxf(mval, __shfl_xor(mval, d));

    // pass 2: chunked — weights lane-parallel, redistribute via shfl,
    // accumulate weighted h rows (256B per edge, fp16).
    float sacc = 0.f, a0 = 0.f, a1 = 0.f;
    for (int base = start; base < end; base += 64) {
        int e = base + lane;
        int sl = 0;
        float wl = 0.f;
        if (e < end) {
            sl = col[e];
            float a = as_[sl] + adv;
            a = (a > 0.f) ? a : NEG_SLOPE * a;
            wl = __expf(a - mval);
        }
        sacc += wl;
        int cnt = min(64, end - base);
        for (int i = 0; i < cnt; ++i) {
            float w = __shfl(wl, i);
            int s = __shfl(sl, i);
            float2 f = __half22float2(h2[(size_t)s * 64 + lane]);
            a0 += w * f.x;
            a1 += w * f.y;
        }
    }
    #pragma unroll
    for (int d = 32; d >= 1; d >>= 1) sacc += __shfl_xor(sacc, d);

    // self-loop contribution (identical on all lanes for sacc; per-lane for h)
    float w_self = __expf(self_a - mval);
    sacc += w_self;
    {
        float2 f = __half22float2(h2[(size_t)v * 64 + lane]);
        a0 += w_self * f.x;
        a1 += w_self * f.y;
    }
    float inv = 1.f / (sacc + SM_EPS);

    // epilogue: residual + bias + LayerNorm + ReLU
    float2 xr = *(const float2*)(xin + (size_t)v * D + lane * 2);
    float y0 = xr.x + a0 * inv + bias[lane * 2];
    float y1 = xr.y + a1 * inv + bias[lane * 2 + 1];

    float s2 = y0 + y1;
    #pragma unroll
    for (int d = 32; d >= 1; d >>= 1) s2 += __shfl_xor(s2, d);
    float mu = s2 * (1.f / 128.f);
    float d0 = y0 - mu, d1 = y1 - mu;
    float vs = d0 * d0 + d1 * d1;
    #pragma unroll
    for (int d = 32; d >= 1; d >>= 1) vs += __shfl_xor(vs, d);
    float rstd = rsqrtf(vs * (1.f / 128.f) + LN_EPS);

    float o0 = d0 * rstd * gamma[lane * 2] + beta[lane * 2];
    float o1 = d1 * rstd * gamma[lane * 2 + 1] + beta[lane * 2 + 1];
    o0 = fmaxf(o0, 0.f);
    o1 = fmaxf(o1, 0.f);
    *(float2*)(xout + (size_t)v * D + lane * 2) = make_float2(o0, o1);
}

// ---------------- launch ----------------

extern "C" void kernel_launch(void* const* d_in, const int* in_sizes, int n_in,
                              void* d_out, int out_size, void* d_ws, size_t ws_size,
                              hipStream_t stream) {
    const float* x       = (const float*)d_in[0];
    const int*   edge    = (const int*)d_in[1];
    const float* W       = (const float*)d_in[2];
    const float* att_src = (const float*)d_in[3];
    const float* att_dst = (const float*)d_in[4];
    const float* bias    = (const float*)d_in[5];
    const float* gamma   = (const float*)d_in[6];
    const float* beta    = (const float*)d_in[7];
    float* out = (float*)d_out;

    const int N = in_sizes[0] / D;       // 100000
    const int E = in_sizes[1] / 2;       // 1600000

    const int* src = edge;
    const int* dst = edge + E;

    // ---- workspace carve (512B-aligned regions) ----
    char* ws = (char*)d_ws;
    size_t off = 0;
    auto carve = [&](size_t bytes) -> char* {
        char* p = ws + off;
        off = (off + bytes + 511) & ~(size_t)511;
        return p;
    };
    int*    rowptr = (int*)carve((size_t)(N + 1) * 4);
    int*    cursor = (int*)carve((size_t)N * 4);       // doubles as deg
    int*    bsums  = (int*)carve(512 * 4);
    int*    col    = (int*)carve((size_t)E * 4);
    __half* h      = (__half*)carve((size_t)N * D * 2);
    float*  as_    = (float*)carve((size_t)N * 4);
    float*  ad_    = (float*)carve((size_t)N * 4);
    float*  x1     = (float*)carve((size_t)N * D * 4);
    (void)ws_size;

    const int TPB = 256;
    int nbN  = (N + TPB - 1) / TPB;       // 391 (<=512 for scanB)
    int nbE  = (E + TPB - 1) / TPB;

    // ---- CSR build (deg/cursor shared buffer) ----
    hipMemsetAsync(cursor, 0, (size_t)N * 4, stream);
    hist_dst<<<nbE, TPB, 0, stream>>>(dst, E, cursor);
    scanA<<<nbN, TPB, 0, stream>>>(cursor, N, rowptr, bsums);
    scanB<<<1, 512, 0, stream>>>(bsums, nbN);
    scanC<<<nbN, TPB, 0, stream>>>(rowptr, bsums, cursor, N, E);
    fill_csr<<<nbE, TPB, 0, stream>>>(src, dst, E, rowptr, cursor, col);

    // ---- 3 levels (x -> x1 -> x1 -> out; in-place agg is row-exclusive) ----
    int gemmGrid = (N + 63) / 64;             // 1563
    int aggGrid  = (N * 64 + TPB - 1) / TPB;  // wave-per-node: N waves, 4/block

    const float* xin = x;
    float* bufs[3] = { x1, x1, out };
    for (int l = 0; l < 3; ++l) {
        const float* Wl  = W + (size_t)l * D * D;
        const float* asl = att_src + (size_t)l * D;
        const float* adl = att_dst + (size_t)l * D;
        const float* bl  = bias + (size_t)l * D;
        const float* gl  = gamma + (size_t)l * D;
        const float* btl = beta + (size_t)l * D;
        float* xout = bufs[l];

        gemm_alpha<<<gemmGrid, TPB, 0, stream>>>(xin, Wl, asl, adl, h, as_, ad_, N);
        aggregate<<<aggGrid, TPB, 0, stream>>>(xin, h, as_, ad_, col, rowptr,
                                               bl, gl, btl, xout, N);
        xin = xout;
    }
}

// Round 9
// 666.494 us; speedup vs baseline: 1.3757x; 1.2198x over previous
//
#include <hip/hip_runtime.h>
#include <hip/hip_fp16.h>
#include <cstdint>

#define D 128
#define NEG_SLOPE 0.2f
#define LN_EPS 1e-5f
#define SM_EPS 1e-16f

// ---------------- CSR build (real edges only; self-loops handled analytically) ----

__global__ void hist_dst(const int* __restrict__ dst, int E, int* __restrict__ deg) {
    int e = blockIdx.x * blockDim.x + threadIdx.x;
    if (e < E) atomicAdd(&deg[dst[e]], 1);
}

__global__ void scanA(const int* __restrict__ deg, int n,
                      int* __restrict__ excl, int* __restrict__ bsums) {
    __shared__ int s[256];
    int t = threadIdx.x;
    int v = blockIdx.x * 256 + t;
    int d = (v < n) ? deg[v] : 0;
    s[t] = d;
    __syncthreads();
    for (int off = 1; off < 256; off <<= 1) {
        int tv = (t >= off) ? s[t - off] : 0;
        __syncthreads();
        s[t] += tv;
        __syncthreads();
    }
    if (v < n) excl[v] = s[t] - d;
    if (t == 255) bsums[blockIdx.x] = s[255];
}

// parallel exclusive scan of block sums (nb <= 512)
__global__ void scanB(int* __restrict__ bsums, int nb) {
    __shared__ int s[512];
    int t = threadIdx.x;
    int v = (t < nb) ? bsums[t] : 0;
    s[t] = v;
    __syncthreads();
    for (int off = 1; off < 512; off <<= 1) {
        int tv = (t >= off) ? s[t - off] : 0;
        __syncthreads();
        s[t] += tv;
        __syncthreads();
    }
    if (t < nb) bsums[t] = s[t] - v;   // exclusive
}

// rowptr += block offset; also zero cursor for fill_csr
__global__ void scanC(int* __restrict__ rowptr, const int* __restrict__ bsums,
                      int* __restrict__ cursor, int n, int total) {
    int v = blockIdx.x * blockDim.x + threadIdx.x;
    if (v < n) { rowptr[v] += bsums[v >> 8]; cursor[v] = 0; }
    if (v == 0) rowptr[n] = total;
}

__global__ void fill_csr(const int* __restrict__ src, const int* __restrict__ dst,
                         int E, const int* __restrict__ rowptr,
                         int* __restrict__ cursor, int* __restrict__ col) {
    int e = blockIdx.x * blockDim.x + threadIdx.x;
    if (e >= E) return;
    int d = dst[e];
    int p = rowptr[d] + atomicAdd(&cursor[d], 1);
    col[p] = src[e];
}

// ---------------- GEMM h = x@W (h stored fp16) with alpha epilogue ----------------

__global__ __launch_bounds__(256) void gemm_alpha(
        const float* __restrict__ x, const float* __restrict__ W,
        const float* __restrict__ asrc, const float* __restrict__ adst,
        __half* __restrict__ h, float* __restrict__ as_, float* __restrict__ ad_, int n) {
    __shared__ float sX[64][D];
    int t = threadIdx.x;
    int row0 = blockIdx.x * 64;

    const float4* xv = (const float4*)x;
    #pragma unroll
    for (int i = 0; i < 8; ++i) {
        int fid = i * 256 + t;
        int r = fid >> 5;
        int c4 = fid & 31;
        int gr = row0 + r;
        float4 val = (gr < n) ? xv[(size_t)gr * 32 + c4] : make_float4(0.f, 0.f, 0.f, 0.f);
        ((float4*)&sX[r][0])[c4] = val;
    }
    __syncthreads();

    int g = t >> 5, m = t & 31;
    int rbase = g * 8;
    float4 acc[8];
    #pragma unroll
    for (int r = 0; r < 8; ++r) acc[r] = make_float4(0.f, 0.f, 0.f, 0.f);

    const float4* Wv = (const float4*)W;
    #pragma unroll 4
    for (int k = 0; k < D; ++k) {
        float4 w = Wv[k * 32 + m];
        #pragma unroll
        for (int r = 0; r < 8; ++r) {
            float xval = sX[rbase + r][k];
            acc[r].x += xval * w.x;
            acc[r].y += xval * w.y;
            acc[r].z += xval * w.z;
            acc[r].w += xval * w.w;
        }
    }

    float4 a_s = ((const float4*)asrc)[m];
    float4 a_d = ((const float4*)adst)[m];
    #pragma unroll
    for (int r = 0; r < 8; ++r) {
        int gr = row0 + rbase + r;
        if (gr < n) {
            union { __half2 h2[2]; float2 f2; } u;
            u.h2[0] = __floats2half2_rn(acc[r].x, acc[r].y);
            u.h2[1] = __floats2half2_rn(acc[r].z, acc[r].w);
            ((float2*)(h + (size_t)gr * D))[m] = u.f2;
            float ps = acc[r].x * a_s.x + acc[r].y * a_s.y + acc[r].z * a_s.z + acc[r].w * a_s.w;
            float pd = acc[r].x * a_d.x + acc[r].y * a_d.y + acc[r].z * a_d.z + acc[r].w * a_d.w;
            #pragma unroll
            for (int d = 16; d >= 1; d >>= 1) {
                ps += __shfl_xor(ps, d);
                pd += __shfl_xor(pd, d);
            }
            if (m == 0) { as_[gr] = ps; ad_[gr] = pd; }
        }
    }
}

// ---------------- fused softmax-aggregate + residual + LN + ReLU ----------------
// one wave per dst node. Pass 1: 64-lane edge scan stashes (src, leaky logit)
// in per-wave LDS. Pass 2: 4x16-lane groups, one edge per group per iter —
// full 256B h row per group (16 lanes x 16B), no shfl in inner loop, 4 edges
// of MLP per wave instruction. Cross-group shfl_xor(16/32) combine; LN within
// 16-lane group; lanes 0-15 store. Self-loop analytic. xout==xin safe.

__global__ __launch_bounds__(256) void aggregate(
        const float* __restrict__ xin, const __half* __restrict__ h,
        const float* __restrict__ as_, const float* __restrict__ ad_,
        const int* __restrict__ col, const int* __restrict__ rowptr,
        const float* __restrict__ bias, const float* __restrict__ gamma,
        const float* __restrict__ beta, float* __restrict__ xout, int n) {
    __shared__ int   sS[4][64];
    __shared__ float sA[4][64];
    int tid = threadIdx.x;
    int wslot = tid >> 6;
    int lane = tid & 63;
    int wid = (int)((blockIdx.x * blockDim.x + tid) >> 6);
    if (wid >= n) return;
    int v = wid;
    int grp = lane >> 4;     // 0..3
    int gl  = lane & 15;     // 0..15
    int start = rowptr[v], end = rowptr[v + 1];
    float adv = ad_[v];
    float self_a = as_[v] + adv;
    self_a = (self_a > 0.f) ? self_a : NEG_SLOPE * self_a;

    // pass 1: segment max over real edges; stash first chunk in LDS
    float mval = self_a;
    for (int cb = start; cb < end; cb += 64) {
        int e = cb + lane;
        int   s_l = 0;
        float a_l = -1e30f;
        if (e < end) {
            s_l = col[e];
            float aa = as_[s_l] + adv;
            a_l = (aa > 0.f) ? aa : NEG_SLOPE * aa;
        }
        if (cb == start) { sS[wslot][lane] = s_l; sA[wslot][lane] = a_l; }
        mval = fmaxf(mval, a_l);
    }
    #pragma unroll
    for (int d = 32; d >= 1; d >>= 1) mval = fmaxf(mval, __shfl_xor(mval, d));

    // pass 2: grouped edge aggregation, weights from LDS
    float sacc = 0.f;
    float acc[8];
    #pragma unroll
    for (int j = 0; j < 8; ++j) acc[j] = 0.f;

    for (int cb = start; cb < end; cb += 64) {
        if (cb != start) {   // deg > 64 only (rare): re-stash this chunk
            int e = cb + lane;
            int   s_l = 0;
            float a_l = -1e30f;
            if (e < end) {
                s_l = col[e];
                float aa = as_[s_l] + adv;
                a_l = (aa > 0.f) ? aa : NEG_SLOPE * aa;
            }
            sS[wslot][lane] = s_l; sA[wslot][lane] = a_l;
        }
        int cnt = min(64, end - cb);
        for (int i = grp; i < cnt; i += 4) {
            int s = sS[wslot][i];
            float w = __expf(sA[wslot][i] - mval);
            sacc += w;
            union { float4 f4; __half2 h2[4]; } u;
            u.f4 = ((const float4*)(h + (size_t)s * D))[gl];
            #pragma unroll
            for (int j = 0; j < 4; ++j) {
                float2 f = __half22float2(u.h2[j]);
                acc[2*j]   += w * f.x;
                acc[2*j+1] += w * f.y;
            }
        }
    }

    // cross-group combine (groups of 16)
    sacc += __shfl_xor(sacc, 16);
    sacc += __shfl_xor(sacc, 32);
    #pragma unroll
    for (int j = 0; j < 8; ++j) {
        acc[j] += __shfl_xor(acc[j], 16);
        acc[j] += __shfl_xor(acc[j], 32);
    }

    // self-loop contribution (once, after combine)
    float w_self = __expf(self_a - mval);
    sacc += w_self;
    {
        union { float4 f4; __half2 h2[4]; } u;
        u.f4 = ((const float4*)(h + (size_t)v * D))[gl];
        #pragma unroll
        for (int j = 0; j < 4; ++j) {
            float2 f = __half22float2(u.h2[j]);
            acc[2*j]   += w_self * f.x;
            acc[2*j+1] += w_self * f.y;
        }
    }
    float inv = 1.f / (sacc + SM_EPS);

    // epilogue on features f = gl*8 + j (all lanes compute; lanes 0-15 store)
    const float4* xr = (const float4*)(xin + (size_t)v * D) + gl * 2;
    float4 xa = xr[0], xb = xr[1];
    const float4* b4 = (const float4*)bias  + gl * 2;
    float4 ba = b4[0], bb = b4[1];
    float y[8];
    y[0] = xa.x + acc[0] * inv + ba.x;
    y[1] = xa.y + acc[1] * inv + ba.y;
    y[2] = xa.z + acc[2] * inv + ba.z;
    y[3] = xa.w + acc[3] * inv + ba.w;
    y[4] = xb.x + acc[4] * inv + bb.x;
    y[5] = xb.y + acc[5] * inv + bb.y;
    y[6] = xb.z + acc[6] * inv + bb.z;
    y[7] = xb.w + acc[7] * inv + bb.w;

    float s2 = 0.f;
    #pragma unroll
    for (int j = 0; j < 8; ++j) s2 += y[j];
    #pragma unroll
    for (int d = 8; d >= 1; d >>= 1) s2 += __shfl_xor(s2, d);
    float mu = s2 * (1.f / 128.f);
    float vs = 0.f;
    #pragma unroll
    for (int j = 0; j < 8; ++j) { float dd = y[j] - mu; vs += dd * dd; }
    #pragma unroll
    for (int d = 8; d >= 1; d >>= 1) vs += __shfl_xor(vs, d);
    float rstd = rsqrtf(vs * (1.f / 128.f) + LN_EPS);

    const float4* g4 = (const float4*)gamma + gl * 2;
    const float4* t4 = (const float4*)beta  + gl * 2;
    float4 ga = g4[0], gb = g4[1];
    float4 ta = t4[0], tb = t4[1];
    float4 oa, ob;
    oa.x = fmaxf((y[0] - mu) * rstd * ga.x + ta.x, 0.f);
    oa.y = fmaxf((y[1] - mu) * rstd * ga.y + ta.y, 0.f);
    oa.z = fmaxf((y[2] - mu) * rstd * ga.z + ta.z, 0.f);
    oa.w = fmaxf((y[3] - mu) * rstd * ga.w + ta.w, 0.f);
    ob.x = fmaxf((y[4] - mu) * rstd * gb.x + tb.x, 0.f);
    ob.y = fmaxf((y[5] - mu) * rstd * gb.y + tb.y, 0.f);
    ob.z = fmaxf((y[6] - mu) * rstd * gb.z + tb.z, 0.f);
    ob.w = fmaxf((y[7] - mu) * rstd * gb.w + tb.w, 0.f);

    if (lane < 16) {
        float4* o4 = (float4*)(xout + (size_t)v * D) + gl * 2;
        o4[0] = oa;
        o4[1] = ob;
    }
}

// ---------------- launch ----------------

extern "C" void kernel_launch(void* const* d_in, const int* in_sizes, int n_in,
                              void* d_out, int out_size, void* d_ws, size_t ws_size,
                              hipStream_t stream) {
    const float* x       = (const float*)d_in[0];
    const int*   edge    = (const int*)d_in[1];
    const float* W       = (const float*)d_in[2];
    const float* att_src = (const float*)d_in[3];
    const float* att_dst = (const float*)d_in[4];
    const float* bias    = (const float*)d_in[5];
    const float* gamma   = (const float*)d_in[6];
    const float* beta    = (const float*)d_in[7];
    float* out = (float*)d_out;

    const int N = in_sizes[0] / D;       // 100000
    const int E = in_sizes[1] / 2;       // 1600000

    const int* src = edge;
    const int* dst = edge + E;

    // ---- workspace carve (512B-aligned regions) ----
    char* ws = (char*)d_ws;
    size_t off = 0;
    auto carve = [&](size_t bytes) -> char* {
        char* p = ws + off;
        off = (off + bytes + 511) & ~(size_t)511;
        return p;
    };
    int*    rowptr = (int*)carve((size_t)(N + 1) * 4);
    int*    cursor = (int*)carve((size_t)N * 4);       // doubles as deg
    int*    bsums  = (int*)carve(512 * 4);
    int*    col    = (int*)carve((size_t)E * 4);
    __half* h      = (__half*)carve((size_t)N * D * 2);
    float*  as_    = (float*)carve((size_t)N * 4);
    float*  ad_    = (float*)carve((size_t)N * 4);
    float*  x1     = (float*)carve((size_t)N * D * 4);
    (void)ws_size;

    const int TPB = 256;
    int nbN  = (N + TPB - 1) / TPB;       // 391 (<=512 for scanB)
    int nbE  = (E + TPB - 1) / TPB;

    // ---- CSR build (deg/cursor shared buffer) ----
    hipMemsetAsync(cursor, 0, (size_t)N * 4, stream);
    hist_dst<<<nbE, TPB, 0, stream>>>(dst, E, cursor);
    scanA<<<nbN, TPB, 0, stream>>>(cursor, N, rowptr, bsums);
    scanB<<<1, 512, 0, stream>>>(bsums, nbN);
    scanC<<<nbN, TPB, 0, stream>>>(rowptr, bsums, cursor, N, E);
    fill_csr<<<nbE, TPB, 0, stream>>>(src, dst, E, rowptr, cursor, col);

    // ---- 3 levels (x -> x1 -> x1 -> out; in-place agg is row-exclusive) ----
    int gemmGrid = (N + 63) / 64;             // 1563
    int aggGrid  = (N * 64 + TPB - 1) / TPB;  // wave-per-node

    const float* xin = x;
    float* bufs[3] = { x1, x1, out };
    for (int l = 0; l < 3; ++l) {
        const float* Wl  = W + (size_t)l * D * D;
        const float* asl = att_src + (size_t)l * D;
        const float* adl = att_dst + (size_t)l * D;
        const float* bl  = bias + (size_t)l * D;
        const float* gl  = gamma + (size_t)l * D;
        const float* btl = beta + (size_t)l * D;
        float* xout = bufs[l];

        gemm_alpha<<<gemmGrid, TPB, 0, stream>>>(xin, Wl, asl, adl, h, as_, ad_, N);
        aggregate<<<aggGrid, TPB, 0, stream>>>(xin, h, as_, ad_, col, rowptr,
                                               bl, gl, btl, xout, N);
        xin = xout;
    }
}

// Round 10
// 626.297 us; speedup vs baseline: 1.4640x; 1.0642x over previous
//
#include <hip/hip_runtime.h>
#include <hip/hip_fp16.h>
#include <cstdint>

#define D 128
#define NEG_SLOPE 0.2f
#define LN_EPS 1e-5f
#define SM_EPS 1e-16f

typedef _Float16 f16x8 __attribute__((ext_vector_type(8)));
typedef float f32x4 __attribute__((ext_vector_type(4)));

// ---------------- CSR build (real edges only; self-loops analytic) ----------------

__global__ void hist_dst(const int* __restrict__ dst, int E, int* __restrict__ deg) {
    int e = blockIdx.x * blockDim.x + threadIdx.x;
    if (e < E) atomicAdd(&deg[dst[e]], 1);
}

__global__ void scanA(const int* __restrict__ deg, int n,
                      int* __restrict__ excl, int* __restrict__ bsums) {
    __shared__ int s[256];
    int t = threadIdx.x;
    int v = blockIdx.x * 256 + t;
    int d = (v < n) ? deg[v] : 0;
    s[t] = d;
    __syncthreads();
    for (int off = 1; off < 256; off <<= 1) {
        int tv = (t >= off) ? s[t - off] : 0;
        __syncthreads();
        s[t] += tv;
        __syncthreads();
    }
    if (v < n) excl[v] = s[t] - d;
    if (t == 255) bsums[blockIdx.x] = s[255];
}

__global__ void scanB(int* __restrict__ bsums, int nb) {
    __shared__ int s[512];
    int t = threadIdx.x;
    int v = (t < nb) ? bsums[t] : 0;
    s[t] = v;
    __syncthreads();
    for (int off = 1; off < 512; off <<= 1) {
        int tv = (t >= off) ? s[t - off] : 0;
        __syncthreads();
        s[t] += tv;
        __syncthreads();
    }
    if (t < nb) bsums[t] = s[t] - v;   // exclusive
}

__global__ void scanC(int* __restrict__ rowptr, const int* __restrict__ bsums,
                      int* __restrict__ cursor, int n, int total) {
    int v = blockIdx.x * blockDim.x + threadIdx.x;
    if (v < n) { rowptr[v] += bsums[v >> 8]; cursor[v] = 0; }
    if (v == 0) rowptr[n] = total;
}

__global__ void fill_csr(const int* __restrict__ src, const int* __restrict__ dst,
                         int E, const int* __restrict__ rowptr,
                         int* __restrict__ cursor, int* __restrict__ col) {
    int e = blockIdx.x * blockDim.x + threadIdx.x;
    if (e >= E) return;
    int d = dst[e];
    int p = rowptr[d] + atomicAdd(&cursor[d], 1);
    col[p] = src[e];
}

// ---------------- prep_w: per level, Wt = W^T (fp16) + w_s = W@a_src, w_d = W@a_dst ----

__global__ void prep_w(const float* __restrict__ W, const float* __restrict__ a_src,
                       const float* __restrict__ a_dst, __half* __restrict__ Wt,
                       float* __restrict__ wsv, float* __restrict__ wdv) {
    int l = blockIdx.x;
    const float* Wl = W + (size_t)l * D * D;
    __half* Wtl = Wt + (size_t)l * D * D;
    int t = threadIdx.x;
    __shared__ float sA[D], sD[D];
    if (t < D) { sA[t] = a_src[l * D + t]; sD[t] = a_dst[l * D + t]; }
    __syncthreads();
    if (t < D) {   // row k = t: dot with a_src/a_dst
        float ps = 0.f, pd = 0.f;
        for (int c = 0; c < D; ++c) {
            float wv = Wl[t * D + c];
            ps += wv * sA[c];
            pd += wv * sD[c];
        }
        wsv[l * D + t] = ps;
        wdv[l * D + t] = pd;
    }
    // transpose to fp16: thread handles column c, k-half kh
    int c = t & 127, kh = t >> 7;
    for (int g = 0; g < 8; ++g) {
        int k0 = kh * 64 + g * 8;
        union { __half hv[8]; float4 f4; } u;
        #pragma unroll
        for (int rr = 0; rr < 8; ++rr) u.hv[rr] = __float2half(Wl[(k0 + rr) * D + c]);
        *(float4*)(Wtl + (size_t)c * D + k0) = u.f4;
    }
}

// ---------------- MFMA GEMM: h = x@W (fp16 in LDS, fp32 acc) + alpha dots ----------------
// block 256 = 4 waves in 2x2; tile 128x128; K=128 in 4 steps of 32.
// LDS: x-tile + Wt-tile, both fp16 [128][128] with XOR swizzle byte^=((row&7)<<4).
// A-frag: row=lane&15, k=(lane>>4)*8+j.  B-frag: col=lane&15 (Wt row), same k.
// C/D: col=lane&15, row=(lane>>4)*4+reg  [learn_hip m89].

__global__ __launch_bounds__(256) void gemm_mfma(
        const float* __restrict__ x, const __half* __restrict__ Wt,
        const float* __restrict__ wsv, const float* __restrict__ wdv,
        __half* __restrict__ h, float* __restrict__ as_, float* __restrict__ ad_, int n) {
    __shared__ char sXa[32768];
    __shared__ char sWb[32768];
    int t = threadIdx.x;
    int row0 = blockIdx.x * 128;
    int lane = t & 63;
    int w = t >> 6;
    int wrow = (w >> 1) * 64;
    int wcol = (w & 1) * 64;

    // stage x (fp32 -> fp16, swizzled)
    const float4* xv = (const float4*)x;
    #pragma unroll
    for (int i = 0; i < 16; ++i) {
        int slot = i * 256 + t;        // 4096 float4 slots
        int r = slot >> 5;
        int c4 = slot & 31;
        int gr = row0 + r;
        float4 v = (gr < n) ? xv[(size_t)gr * 32 + c4] : make_float4(0.f, 0.f, 0.f, 0.f);
        union { __half2 q[2]; float2 f; } u;
        u.q[0] = __floats2half2_rn(v.x, v.y);
        u.q[1] = __floats2half2_rn(v.z, v.w);
        *(float2*)(sXa + r * 256 + ((c4 * 8) ^ ((r & 7) << 4))) = u.f;
    }
    // stage Wt (already fp16, swizzled)
    const float4* wv = (const float4*)Wt;
    #pragma unroll
    for (int i = 0; i < 8; ++i) {
        int chunk = i * 256 + t;       // 2048 16B chunks
        int r = chunk >> 4;
        int c16 = chunk & 15;
        float4 v = wv[chunk];
        *(float4*)(sWb + r * 256 + ((c16 * 16) ^ ((r & 7) << 4))) = v;
    }
    __syncthreads();

    f32x4 acc[4][4];
    #pragma unroll
    for (int a = 0; a < 4; ++a)
        #pragma unroll
        for (int b = 0; b < 4; ++b) acc[a][b] = (f32x4){0.f, 0.f, 0.f, 0.f};

    #pragma unroll
    for (int ks = 0; ks < 4; ++ks) {
        int kbyte = ks * 64 + (lane >> 4) * 16;
        f16x8 aF[4], bF[4];
        #pragma unroll
        for (int tt = 0; tt < 4; ++tt) {
            int ra = wrow + tt * 16 + (lane & 15);
            aF[tt] = *(f16x8*)(sXa + ra * 256 + (kbyte ^ ((ra & 7) << 4)));
            int rb = wcol + tt * 16 + (lane & 15);
            bF[tt] = *(f16x8*)(sWb + rb * 256 + (kbyte ^ ((rb & 7) << 4)));
        }
        #pragma unroll
        for (int tr = 0; tr < 4; ++tr)
            #pragma unroll
            for (int tc = 0; tc < 4; ++tc)
                acc[tr][tc] = __builtin_amdgcn_mfma_f32_16x16x32_f16(aF[tr], bF[tc], acc[tr][tc], 0, 0, 0);
    }

    // store h fp16
    #pragma unroll
    for (int tr = 0; tr < 4; ++tr) {
        #pragma unroll
        for (int reg = 0; reg < 4; ++reg) {
            int gr = row0 + wrow + tr * 16 + (lane >> 4) * 4 + reg;
            if (gr < n) {
                #pragma unroll
                for (int tc = 0; tc < 4; ++tc) {
                    int gc = wcol + tc * 16 + (lane & 15);
                    h[(size_t)gr * D + gc] = __float2half(acc[tr][tc][reg]);
                }
            }
        }
    }

    // alpha dots from LDS x-tile: 2 threads per row (hh = k-half)
    int r = t >> 1, hh = t & 1;
    float ps = 0.f, pd = 0.f;
    const float4* s4 = (const float4*)wsv + hh * 16;
    const float4* d4 = (const float4*)wdv + hh * 16;
    #pragma unroll
    for (int g = 0; g < 8; ++g) {
        int kbyte = hh * 128 + g * 16;
        f16x8 xa = *(f16x8*)(sXa + r * 256 + (kbyte ^ ((r & 7) << 4)));
        float4 sa = s4[g * 2], sb = s4[g * 2 + 1];
        float4 da = d4[g * 2], db = d4[g * 2 + 1];
        ps += (float)xa[0] * sa.x + (float)xa[1] * sa.y + (float)xa[2] * sa.z + (float)xa[3] * sa.w
            + (float)xa[4] * sb.x + (float)xa[5] * sb.y + (float)xa[6] * sb.z + (float)xa[7] * sb.w;
        pd += (float)xa[0] * da.x + (float)xa[1] * da.y + (float)xa[2] * da.z + (float)xa[3] * da.w
            + (float)xa[4] * db.x + (float)xa[5] * db.y + (float)xa[6] * db.z + (float)xa[7] * db.w;
    }
    ps += __shfl_xor(ps, 1);
    pd += __shfl_xor(pd, 1);
    if (hh == 0 && row0 + r < n) { as_[row0 + r] = ps; ad_[row0 + r] = pd; }
}

// ---------------- fused softmax-aggregate + residual + LN + ReLU ----------------
// one wave per dst node; pass 1 stashes (src, packed fp16 weight) in LDS after
// a single expf pass (hoisted out of the inner loop); pass 2: 4x16-lane groups,
// one edge per group per iter, v_pk_fma_f16 accumulate. Self-loop analytic.

__global__ __launch_bounds__(256) void aggregate(
        const float* __restrict__ xin, const __half* __restrict__ h,
        const float* __restrict__ as_, const float* __restrict__ ad_,
        const int* __restrict__ col, const int* __restrict__ rowptr,
        const float* __restrict__ bias, const float* __restrict__ gamma,
        const float* __restrict__ beta, float* __restrict__ xout, int n) {
    __shared__ int     sS[4][64];
    __shared__ __half2 sW[4][64];
    int tid = threadIdx.x;
    int wslot = tid >> 6;
    int lane = tid & 63;
    int wid = (int)((blockIdx.x * blockDim.x + tid) >> 6);
    if (wid >= n) return;
    int v = wid;
    int grp = lane >> 4;
    int gl  = lane & 15;
    int start = rowptr[v], end = rowptr[v + 1];
    float adv = ad_[v];
    float self_a = as_[v] + adv;
    self_a = (self_a > 0.f) ? self_a : NEG_SLOPE * self_a;

    // pass 1: max over edges; keep chunk-0 (src, logit) in regs
    float mval = self_a;
    int   s0 = 0;
    float a0 = -1e30f;
    for (int cb = start; cb < end; cb += 64) {
        int e = cb + lane;
        int   sl = 0;
        float al = -1e30f;
        if (e < end) {
            sl = col[e];
            float aa = as_[sl] + adv;
            al = (aa > 0.f) ? aa : NEG_SLOPE * aa;
        }
        if (cb == start) { s0 = sl; a0 = al; }
        mval = fmaxf(mval, al);
    }
    #pragma unroll
    for (int d = 32; d >= 1; d >>= 1) mval = fmaxf(mval, __shfl_xor(mval, d));

    // weight conversion (chunk 0), stash packed
    float wl = __expf(a0 - mval);      // a0=-inf -> 0
    float sacc = wl;
    sS[wslot][lane] = s0;
    sW[wslot][lane] = __float2half2_rn(wl);

    // pass 2: grouped aggregation, fp16 pk-fma
    __half2 hacc[4];
    #pragma unroll
    for (int j = 0; j < 4; ++j) hacc[j] = __float2half2_rn(0.f);

    const float4* h4 = (const float4*)h;   // 16 float4 per row

    for (int cb = start; cb < end; cb += 64) {
        if (cb != start) {   // deg > 64 only (essentially never at deg~16)
            int e = cb + lane;
            int   sl = 0;
            float al = -1e30f;
            if (e < end) {
                sl = col[e];
                float aa = as_[sl] + adv;
                al = (aa > 0.f) ? aa : NEG_SLOPE * aa;
            }
            float wl2 = __expf(al - mval);
            sacc += wl2;
            sS[wslot][lane] = sl;
            sW[wslot][lane] = __float2half2_rn(wl2);
        }
        int cnt = min(64, end - cb);
        for (int i = grp; i < cnt; i += 4) {
            int s = sS[wslot][i];
            __half2 w2 = sW[wslot][i];
            union { float4 f4; __half2 h2[4]; } u;
            u.f4 = h4[(size_t)s * 16 + gl];
            #pragma unroll
            for (int j = 0; j < 4; ++j) hacc[j] = __hfma2(u.h2[j], w2, hacc[j]);
        }
    }
    #pragma unroll
    for (int d = 32; d >= 1; d >>= 1) sacc += __shfl_xor(sacc, d);

    // unpack to f32, cross-group combine
    float acc[8];
    #pragma unroll
    for (int j = 0; j < 4; ++j) {
        float2 f = __half22float2(hacc[j]);
        acc[2 * j] = f.x;
        acc[2 * j + 1] = f.y;
    }
    #pragma unroll
    for (int j = 0; j < 8; ++j) {
        acc[j] += __shfl_xor(acc[j], 16);
        acc[j] += __shfl_xor(acc[j], 32);
    }

    // self-loop (f32)
    float w_self = __expf(self_a - mval);
    sacc += w_self;
    {
        union { float4 f4; __half2 h2[4]; } u;
        u.f4 = h4[(size_t)v * 16 + gl];
        #pragma unroll
        for (int j = 0; j < 4; ++j) {
            float2 f = __half22float2(u.h2[j]);
            acc[2 * j]     += w_self * f.x;
            acc[2 * j + 1] += w_self * f.y;
        }
    }
    float inv = 1.f / (sacc + SM_EPS);

    // epilogue: residual + bias + LN + ReLU (features f = gl*8 + j)
    const float4* xr = (const float4*)(xin + (size_t)v * D) + gl * 2;
    float4 xa = xr[0], xb = xr[1];
    const float4* b4 = (const float4*)bias + gl * 2;
    float4 ba = b4[0], bb = b4[1];
    float y[8];
    y[0] = xa.x + acc[0] * inv + ba.x;
    y[1] = xa.y + acc[1] * inv + ba.y;
    y[2] = xa.z + acc[2] * inv + ba.z;
    y[3] = xa.w + acc[3] * inv + ba.w;
    y[4] = xb.x + acc[4] * inv + bb.x;
    y[5] = xb.y + acc[5] * inv + bb.y;
    y[6] = xb.z + acc[6] * inv + bb.z;
    y[7] = xb.w + acc[7] * inv + bb.w;

    float s2 = 0.f;
    #pragma unroll
    for (int j = 0; j < 8; ++j) s2 += y[j];
    #pragma unroll
    for (int d = 8; d >= 1; d >>= 1) s2 += __shfl_xor(s2, d);
    float mu = s2 * (1.f / 128.f);
    float vs = 0.f;
    #pragma unroll
    for (int j = 0; j < 8; ++j) { float dd = y[j] - mu; vs += dd * dd; }
    #pragma unroll
    for (int d = 8; d >= 1; d >>= 1) vs += __shfl_xor(vs, d);
    float rstd = rsqrtf(vs * (1.f / 128.f) + LN_EPS);

    const float4* g4 = (const float4*)gamma + gl * 2;
    const float4* t4 = (const float4*)beta + gl * 2;
    float4 ga = g4[0], gb = g4[1];
    float4 ta = t4[0], tb = t4[1];
    float4 oa, ob;
    oa.x = fmaxf((y[0] - mu) * rstd * ga.x + ta.x, 0.f);
    oa.y = fmaxf((y[1] - mu) * rstd * ga.y + ta.y, 0.f);
    oa.z = fmaxf((y[2] - mu) * rstd * ga.z + ta.z, 0.f);
    oa.w = fmaxf((y[3] - mu) * rstd * ga.w + ta.w, 0.f);
    ob.x = fmaxf((y[4] - mu) * rstd * gb.x + tb.x, 0.f);
    ob.y = fmaxf((y[5] - mu) * rstd * gb.y + tb.y, 0.f);
    ob.z = fmaxf((y[6] - mu) * rstd * gb.z + tb.z, 0.f);
    ob.w = fmaxf((y[7] - mu) * rstd * gb.w + tb.w, 0.f);

    if (lane < 16) {
        float4* o4 = (float4*)(xout + (size_t)v * D) + gl * 2;
        o4[0] = oa;
        o4[1] = ob;
    }
}

// ---------------- launch ----------------

extern "C" void kernel_launch(void* const* d_in, const int* in_sizes, int n_in,
                              void* d_out, int out_size, void* d_ws, size_t ws_size,
                              hipStream_t stream) {
    const float* x       = (const float*)d_in[0];
    const int*   edge    = (const int*)d_in[1];
    const float* W       = (const float*)d_in[2];
    const float* att_src = (const float*)d_in[3];
    const float* att_dst = (const float*)d_in[4];
    const float* bias    = (const float*)d_in[5];
    const float* gamma   = (const float*)d_in[6];
    const float* beta    = (const float*)d_in[7];
    float* out = (float*)d_out;

    const int N = in_sizes[0] / D;       // 100000
    const int E = in_sizes[1] / 2;       // 1600000

    const int* src = edge;
    const int* dst = edge + E;

    // ---- workspace carve ----
    char* ws = (char*)d_ws;
    size_t off = 0;
    auto carve = [&](size_t bytes) -> char* {
        char* p = ws + off;
        off = (off + bytes + 511) & ~(size_t)511;
        return p;
    };
    int*    rowptr = (int*)carve((size_t)(N + 1) * 4);
    int*    cursor = (int*)carve((size_t)N * 4);
    int*    bsums  = (int*)carve(512 * 4);
    int*    col    = (int*)carve((size_t)E * 4);
    __half* h      = (__half*)carve((size_t)N * D * 2);
    float*  as_    = (float*)carve((size_t)N * 4);
    float*  ad_    = (float*)carve((size_t)N * 4);
    float*  x1     = (float*)carve((size_t)N * D * 4);
    __half* Wt     = (__half*)carve((size_t)3 * D * D * 2);
    float*  wsv    = (float*)carve((size_t)3 * D * 4);
    float*  wdv    = (float*)carve((size_t)3 * D * 4);
    (void)ws_size;

    const int TPB = 256;
    int nbN = (N + TPB - 1) / TPB;       // 391 (<=512 for scanB)
    int nbE = (E + TPB - 1) / TPB;

    // ---- W prep (independent of CSR) ----
    prep_w<<<3, TPB, 0, stream>>>(W, att_src, att_dst, Wt, wsv, wdv);

    // ---- CSR build ----
    hipMemsetAsync(cursor, 0, (size_t)N * 4, stream);
    hist_dst<<<nbE, TPB, 0, stream>>>(dst, E, cursor);
    scanA<<<nbN, TPB, 0, stream>>>(cursor, N, rowptr, bsums);
    scanB<<<1, 512, 0, stream>>>(bsums, nbN);
    scanC<<<nbN, TPB, 0, stream>>>(rowptr, bsums, cursor, N, E);
    fill_csr<<<nbE, TPB, 0, stream>>>(src, dst, E, rowptr, cursor, col);

    // ---- 3 levels (x -> x1 -> x1 -> out) ----
    int gemmGrid = (N + 127) / 128;           // 782
    int aggGrid  = (N * 64 + TPB - 1) / TPB;  // wave-per-node

    const float* xin = x;
    float* bufs[3] = { x1, x1, out };
    for (int l = 0; l < 3; ++l) {
        const __half* Wtl = Wt + (size_t)l * D * D;
        const float*  wsl = wsv + (size_t)l * D;
        const float*  wdl = wdv + (size_t)l * D;
        const float*  bl  = bias + (size_t)l * D;
        const float*  gl  = gamma + (size_t)l * D;
        const float*  btl = beta + (size_t)l * D;
        float* xout = bufs[l];

        gemm_mfma<<<gemmGrid, TPB, 0, stream>>>(xin, Wtl, wsl, wdl, h, as_, ad_, N);
        aggregate<<<aggGrid, TPB, 0, stream>>>(xin, h, as_, ad_, col, rowptr,
                                               bl, gl, btl, xout, N);
        xin = xout;
    }
}

// Round 12
// 579.804 us; speedup vs baseline: 1.5814x; 1.0802x over previous
//
#include <hip/hip_runtime.h>
#include <hip/hip_fp16.h>
#include <cstdint>

#define D 128
#define NEG_SLOPE 0.2f
#define LN_EPS 1e-5f
#define SM_EPS 1e-16f

typedef _Float16 f16x8 __attribute__((ext_vector_type(8)));
typedef float f32x4 __attribute__((ext_vector_type(4)));

// ---------------- CSR build (real edges only; self-loops analytic) ----------------
// hist_dst also emits each edge's within-row rank (atomicAdd return), so
// fill_csr needs no cursor atomic; its scattered col store uses atomicExch
// (executes at the device-scope point -> no cross-XCD dirty-line write
// amplification; r10 profile: plain stores cost 107MB WRITE_SIZE = E*64B).

__global__ void hist_dst(const int* __restrict__ dst, int E,
                         int* __restrict__ deg, int* __restrict__ rank) {
    int e = blockIdx.x * blockDim.x + threadIdx.x;
    if (e < E) rank[e] = atomicAdd(&deg[dst[e]], 1);
}

__global__ void scanA(const int* __restrict__ deg, int n,
                      int* __restrict__ excl, int* __restrict__ bsums) {
    __shared__ int s[256];
    int t = threadIdx.x;
    int v = blockIdx.x * 256 + t;
    int d = (v < n) ? deg[v] : 0;
    s[t] = d;
    __syncthreads();
    for (int off = 1; off < 256; off <<= 1) {
        int tv = (t >= off) ? s[t - off] : 0;
        __syncthreads();
        s[t] += tv;
        __syncthreads();
    }
    if (v < n) excl[v] = s[t] - d;
    if (t == 255) bsums[blockIdx.x] = s[255];
}

__global__ void scanB(int* __restrict__ bsums, int nb) {
    __shared__ int s[512];
    int t = threadIdx.x;
    int v = (t < nb) ? bsums[t] : 0;
    s[t] = v;
    __syncthreads();
    for (int off = 1; off < 512; off <<= 1) {
        int tv = (t >= off) ? s[t - off] : 0;
        __syncthreads();
        s[t] += tv;
        __syncthreads();
    }
    if (t < nb) bsums[t] = s[t] - v;   // exclusive
}

__global__ void scanC(int* __restrict__ rowptr, const int* __restrict__ bsums,
                      int n, int total) {
    int v = blockIdx.x * blockDim.x + threadIdx.x;
    if (v < n) rowptr[v] += bsums[v >> 8];
    if (v == 0) rowptr[n] = total;
}

__global__ void fill_csr(const int* __restrict__ src, const int* __restrict__ dst,
                         const int* __restrict__ rank, int E,
                         const int* __restrict__ rowptr, int* __restrict__ col) {
    int e = blockIdx.x * blockDim.x + threadIdx.x;
    if (e >= E) return;
    int d = dst[e];
    int p = rowptr[d] + rank[e];
    atomicExch(&col[p], src[e]);   // fire-and-forget scattered store
}

// ---------------- prep_w: Wt = W^T (fp16) + w_s = W@a_src, w_d = W@a_dst ----------
// 24 blocks: l = bid/8, part = bid%8 transposes a 128x16 slab via LDS; part 0
// also computes the 128 alpha-dot values.

__global__ void prep_w(const float* __restrict__ W, const float* __restrict__ a_src,
                       const float* __restrict__ a_dst, __half* __restrict__ Wt,
                       float* __restrict__ wsv, float* __restrict__ wdv) {
    int l = blockIdx.x >> 3;
    int part = blockIdx.x & 7;
    const float* Wl = W + (size_t)l * D * D;
    __half* Wtl = Wt + (size_t)l * D * D;
    int t = threadIdx.x;
    int c0 = part * 16;

    __shared__ float sT[128][17];
    #pragma unroll
    for (int i = 0; i < 8; ++i) {
        int id = i * 256 + t;          // 0..2047
        int k = id >> 4, c = id & 15;
        sT[k][c] = Wl[(size_t)k * D + c0 + c];
    }
    __syncthreads();
    {
        int c = t >> 4, kg = t & 15;
        union { __half hv[8]; float4 f4; } u;
        #pragma unroll
        for (int j = 0; j < 8; ++j) u.hv[j] = __float2half(sT[kg * 8 + j][c]);
        *(float4*)(Wtl + (size_t)(c0 + c) * D + kg * 8) = u.f4;
    }

    if (part == 0) {
        __shared__ float sA[D], sD[D];
        if (t < D) { sA[t] = a_src[l * D + t]; sD[t] = a_dst[l * D + t]; }
        __syncthreads();
        if (t < D) {
            float ps = 0.f, pd = 0.f;
            for (int c = 0; c < D; ++c) {
                float wv = Wl[(size_t)t * D + c];
                ps += wv * sA[c];
                pd += wv * sD[c];
            }
            wsv[l * D + t] = ps;
            wdv[l * D + t] = pd;
        }
    }
}

// ---------------- MFMA GEMM: h = x@W (fp16 in LDS, fp32 acc) + alpha dots ----------------

__global__ __launch_bounds__(256) void gemm_mfma(
        const float* __restrict__ x, const __half* __restrict__ Wt,
        const float* __restrict__ wsv, const float* __restrict__ wdv,
        __half* __restrict__ h, float* __restrict__ as_, float* __restrict__ ad_, int n) {
    __shared__ char sXa[32768];
    __shared__ char sWb[32768];
    int t = threadIdx.x;
    int row0 = blockIdx.x * 128;
    int lane = t & 63;
    int w = t >> 6;
    int wrow = (w >> 1) * 64;
    int wcol = (w & 1) * 64;

    const float4* xv = (const float4*)x;
    #pragma unroll
    for (int i = 0; i < 16; ++i) {
        int slot = i * 256 + t;
        int r = slot >> 5;
        int c4 = slot & 31;
        int gr = row0 + r;
        float4 v = (gr < n) ? xv[(size_t)gr * 32 + c4] : make_float4(0.f, 0.f, 0.f, 0.f);
        union { __half2 q[2]; float2 f; } u;
        u.q[0] = __floats2half2_rn(v.x, v.y);
        u.q[1] = __floats2half2_rn(v.z, v.w);
        *(float2*)(sXa + r * 256 + ((c4 * 8) ^ ((r & 7) << 4))) = u.f;
    }
    const float4* wv = (const float4*)Wt;
    #pragma unroll
    for (int i = 0; i < 8; ++i) {
        int chunk = i * 256 + t;
        int r = chunk >> 4;
        int c16 = chunk & 15;
        float4 v = wv[chunk];
        *(float4*)(sWb + r * 256 + ((c16 * 16) ^ ((r & 7) << 4))) = v;
    }
    __syncthreads();

    f32x4 acc[4][4];
    #pragma unroll
    for (int a = 0; a < 4; ++a)
        #pragma unroll
        for (int b = 0; b < 4; ++b) acc[a][b] = (f32x4){0.f, 0.f, 0.f, 0.f};

    #pragma unroll
    for (int ks = 0; ks < 4; ++ks) {
        int kbyte = ks * 64 + (lane >> 4) * 16;
        f16x8 aF[4], bF[4];
        #pragma unroll
        for (int tt = 0; tt < 4; ++tt) {
            int ra = wrow + tt * 16 + (lane & 15);
            aF[tt] = *(f16x8*)(sXa + ra * 256 + (kbyte ^ ((ra & 7) << 4)));
            int rb = wcol + tt * 16 + (lane & 15);
            bF[tt] = *(f16x8*)(sWb + rb * 256 + (kbyte ^ ((rb & 7) << 4)));
        }
        #pragma unroll
        for (int tr = 0; tr < 4; ++tr)
            #pragma unroll
            for (int tc = 0; tc < 4; ++tc)
                acc[tr][tc] = __builtin_amdgcn_mfma_f32_16x16x32_f16(aF[tr], bF[tc], acc[tr][tc], 0, 0, 0);
    }

    #pragma unroll
    for (int tr = 0; tr < 4; ++tr) {
        #pragma unroll
        for (int reg = 0; reg < 4; ++reg) {
            int gr = row0 + wrow + tr * 16 + (lane >> 4) * 4 + reg;
            if (gr < n) {
                #pragma unroll
                for (int tc = 0; tc < 4; ++tc) {
                    int gc = wcol + tc * 16 + (lane & 15);
                    h[(size_t)gr * D + gc] = __float2half(acc[tr][tc][reg]);
                }
            }
        }
    }

    // alpha dots from LDS x-tile: 2 threads per row (hh = k-half)
    int r = t >> 1, hh = t & 1;
    float ps = 0.f, pd = 0.f;
    const float4* s4 = (const float4*)wsv + hh * 16;
    const float4* d4 = (const float4*)wdv + hh * 16;
    #pragma unroll
    for (int g = 0; g < 8; ++g) {
        int kbyte = hh * 128 + g * 16;
        f16x8 xa = *(f16x8*)(sXa + r * 256 + (kbyte ^ ((r & 7) << 4)));
        float4 sa = s4[g * 2], sb = s4[g * 2 + 1];
        float4 da = d4[g * 2], db = d4[g * 2 + 1];
        ps += (float)xa[0] * sa.x + (float)xa[1] * sa.y + (float)xa[2] * sa.z + (float)xa[3] * sa.w
            + (float)xa[4] * sb.x + (float)xa[5] * sb.y + (float)xa[6] * sb.z + (float)xa[7] * sb.w;
        pd += (float)xa[0] * da.x + (float)xa[1] * da.y + (float)xa[2] * da.z + (float)xa[3] * da.w
            + (float)xa[4] * db.x + (float)xa[5] * db.y + (float)xa[6] * db.z + (float)xa[7] * db.w;
    }
    ps += __shfl_xor(ps, 1);
    pd += __shfl_xor(pd, 1);
    if (hh == 0 && row0 + r < n) { as_[row0 + r] = ps; ad_[row0 + r] = pd; }
}

// ---------------- fused softmax-aggregate + residual + LN + ReLU ----------------

__global__ __launch_bounds__(256) void aggregate(
        const float* __restrict__ xin, const __half* __restrict__ h,
        const float* __restrict__ as_, const float* __restrict__ ad_,
        const int* __restrict__ col, const int* __restrict__ rowptr,
        const float* __restrict__ bias, const float* __restrict__ gamma,
        const float* __restrict__ beta, float* __restrict__ xout, int n) {
    __shared__ int     sS[4][64];
    __shared__ __half2 sW[4][64];
    int tid = threadIdx.x;
    int wslot = tid >> 6;
    int lane = tid & 63;
    int wid = (int)((blockIdx.x * blockDim.x + tid) >> 6);
    if (wid >= n) return;
    int v = wid;
    int grp = lane >> 4;
    int gl  = lane & 15;
    int start = rowptr[v], end = rowptr[v + 1];
    float adv = ad_[v];
    float self_a = as_[v] + adv;
    self_a = (self_a > 0.f) ? self_a : NEG_SLOPE * self_a;

    float mval = self_a;
    int   s0 = 0;
    float a0 = -1e30f;
    for (int cb = start; cb < end; cb += 64) {
        int e = cb + lane;
        int   sl = 0;
        float al = -1e30f;
        if (e < end) {
            sl = col[e];
            float aa = as_[sl] + adv;
            al = (aa > 0.f) ? aa : NEG_SLOPE * aa;
        }
        if (cb == start) { s0 = sl; a0 = al; }
        mval = fmaxf(mval, al);
    }
    #pragma unroll
    for (int d = 32; d >= 1; d >>= 1) mval = fmaxf(mval, __shfl_xor(mval, d));

    float wl = __expf(a0 - mval);
    float sacc = wl;
    sS[wslot][lane] = s0;
    sW[wslot][lane] = __float2half2_rn(wl);

    __half2 hacc[4];
    #pragma unroll
    for (int j = 0; j < 4; ++j) hacc[j] = __float2half2_rn(0.f);

    const float4* h4 = (const float4*)h;

    for (int cb = start; cb < end; cb += 64) {
        if (cb != start) {
            int e = cb + lane;
            int   sl = 0;
            float al = -1e30f;
            if (e < end) {
                sl = col[e];
                float aa = as_[sl] + adv;
                al = (aa > 0.f) ? aa : NEG_SLOPE * aa;
            }
            float wl2 = __expf(al - mval);
            sacc += wl2;
            sS[wslot][lane] = sl;
            sW[wslot][lane] = __float2half2_rn(wl2);
        }
        int cnt = min(64, end - cb);
        for (int i = grp; i < cnt; i += 4) {
            int s = sS[wslot][i];
            __half2 w2 = sW[wslot][i];
            union { float4 f4; __half2 h2[4]; } u;
            u.f4 = h4[(size_t)s * 16 + gl];
            #pragma unroll
            for (int j = 0; j < 4; ++j) hacc[j] = __hfma2(u.h2[j], w2, hacc[j]);
        }
    }
    #pragma unroll
    for (int d = 32; d >= 1; d >>= 1) sacc += __shfl_xor(sacc, d);

    float acc[8];
    #pragma unroll
    for (int j = 0; j < 4; ++j) {
        float2 f = __half22float2(hacc[j]);
        acc[2 * j] = f.x;
        acc[2 * j + 1] = f.y;
    }
    #pragma unroll
    for (int j = 0; j < 8; ++j) {
        acc[j] += __shfl_xor(acc[j], 16);
        acc[j] += __shfl_xor(acc[j], 32);
    }

    float w_self = __expf(self_a - mval);
    sacc += w_self;
    {
        union { float4 f4; __half2 h2[4]; } u;
        u.f4 = h4[(size_t)v * 16 + gl];
        #pragma unroll
        for (int j = 0; j < 4; ++j) {
            float2 f = __half22float2(u.h2[j]);
            acc[2 * j]     += w_self * f.x;
            acc[2 * j + 1] += w_self * f.y;
        }
    }
    float inv = 1.f / (sacc + SM_EPS);

    const float4* xr = (const float4*)(xin + (size_t)v * D) + gl * 2;
    float4 xa = xr[0], xb = xr[1];
    const float4* b4 = (const float4*)bias + gl * 2;
    float4 ba = b4[0], bb = b4[1];
    float y[8];
    y[0] = xa.x + acc[0] * inv + ba.x;
    y[1] = xa.y + acc[1] * inv + ba.y;
    y[2] = xa.z + acc[2] * inv + ba.z;
    y[3] = xa.w + acc[3] * inv + ba.w;
    y[4] = xb.x + acc[4] * inv + bb.x;
    y[5] = xb.y + acc[5] * inv + bb.y;
    y[6] = xb.z + acc[6] * inv + bb.z;
    y[7] = xb.w + acc[7] * inv + bb.w;

    float s2 = 0.f;
    #pragma unroll
    for (int j = 0; j < 8; ++j) s2 += y[j];
    #pragma unroll
    for (int d = 8; d >= 1; d >>= 1) s2 += __shfl_xor(s2, d);
    float mu = s2 * (1.f / 128.f);
    float vs = 0.f;
    #pragma unroll
    for (int j = 0; j < 8; ++j) { float dd = y[j] - mu; vs += dd * dd; }
    #pragma unroll
    for (int d = 8; d >= 1; d >>= 1) vs += __shfl_xor(vs, d);
    float rstd = rsqrtf(vs * (1.f / 128.f) + LN_EPS);

    const float4* g4 = (const float4*)gamma + gl * 2;
    const float4* t4 = (const float4*)beta + gl * 2;
    float4 ga = g4[0], gb = g4[1];
    float4 ta = t4[0], tb = t4[1];
    float4 oa, ob;
    oa.x = fmaxf((y[0] - mu) * rstd * ga.x + ta.x, 0.f);
    oa.y = fmaxf((y[1] - mu) * rstd * ga.y + ta.y, 0.f);
    oa.z = fmaxf((y[2] - mu) * rstd * ga.z + ta.z, 0.f);
    oa.w = fmaxf((y[3] - mu) * rstd * ga.w + ta.w, 0.f);
    ob.x = fmaxf((y[4] - mu) * rstd * gb.x + tb.x, 0.f);
    ob.y = fmaxf((y[5] - mu) * rstd * gb.y + tb.y, 0.f);
    ob.z = fmaxf((y[6] - mu) * rstd * gb.z + tb.z, 0.f);
    ob.w = fmaxf((y[7] - mu) * rstd * gb.w + tb.w, 0.f);

    if (lane < 16) {
        float4* o4 = (float4*)(xout + (size_t)v * D) + gl * 2;
        o4[0] = oa;
        o4[1] = ob;
    }
}

// ---------------- launch ----------------

extern "C" void kernel_launch(void* const* d_in, const int* in_sizes, int n_in,
                              void* d_out, int out_size, void* d_ws, size_t ws_size,
                              hipStream_t stream) {
    const float* x       = (const float*)d_in[0];
    const int*   edge    = (const int*)d_in[1];
    const float* W       = (const float*)d_in[2];
    const float* att_src = (const float*)d_in[3];
    const float* att_dst = (const float*)d_in[4];
    const float* bias    = (const float*)d_in[5];
    const float* gamma   = (const float*)d_in[6];
    const float* beta    = (const float*)d_in[7];
    float* out = (float*)d_out;

    const int N = in_sizes[0] / D;       // 100000
    const int E = in_sizes[1] / 2;       // 1600000

    const int* src = edge;
    const int* dst = edge + E;

    // ---- workspace carve ----
    char* ws = (char*)d_ws;
    size_t off = 0;
    auto carve = [&](size_t bytes) -> char* {
        char* p = ws + off;
        off = (off + bytes + 511) & ~(size_t)511;
        return p;
    };
    int*    rowptr = (int*)carve((size_t)(N + 1) * 4);
    int*    deg    = (int*)carve((size_t)N * 4);
    int*    bsums  = (int*)carve(512 * 4);
    int*    col    = (int*)carve((size_t)E * 4);
    int*    rank   = (int*)carve((size_t)E * 4);
    __half* h      = (__half*)carve((size_t)N * D * 2);
    float*  as_    = (float*)carve((size_t)N * 4);
    float*  ad_    = (float*)carve((size_t)N * 4);
    float*  x1     = (float*)carve((size_t)N * D * 4);
    __half* Wt     = (__half*)carve((size_t)3 * D * D * 2);
    float*  wsv    = (float*)carve((size_t)3 * D * 4);
    float*  wdv    = (float*)carve((size_t)3 * D * 4);
    (void)ws_size;

    const int TPB = 256;
    int nbN = (N + TPB - 1) / TPB;       // 391 (<=512 for scanB)
    int nbE = (E + TPB - 1) / TPB;

    // ---- W prep (independent of CSR) ----
    prep_w<<<24, TPB, 0, stream>>>(W, att_src, att_dst, Wt, wsv, wdv);

    // ---- CSR build ----
    hipMemsetAsync(deg, 0, (size_t)N * 4, stream);
    hist_dst<<<nbE, TPB, 0, stream>>>(dst, E, deg, rank);
    scanA<<<nbN, TPB, 0, stream>>>(deg, N, rowptr, bsums);
    scanB<<<1, 512, 0, stream>>>(bsums, nbN);
    scanC<<<nbN, TPB, 0, stream>>>(rowptr, bsums, N, E);
    fill_csr<<<nbE, TPB, 0, stream>>>(src, dst, rank, E, rowptr, col);

    // ---- 3 levels (x -> x1 -> x1 -> out) ----
    int gemmGrid = (N + 127) / 128;           // 782
    int aggGrid  = (N * 64 + TPB - 1) / TPB;  // wave-per-node

    const float* xin = x;
    float* bufs[3] = { x1, x1, out };
    for (int l = 0; l < 3; ++l) {
        const __half* Wtl = Wt + (size_t)l * D * D;
        const float*  wsl = wsv + (size_t)l * D;
        const float*  wdl = wdv + (size_t)l * D;
        const float*  bl  = bias + (size_t)l * D;
        const float*  gl  = gamma + (size_t)l * D;
        const float*  btl = beta + (size_t)l * D;
        float* xout = bufs[l];

        gemm_mfma<<<gemmGrid, TPB, 0, stream>>>(xin, Wtl, wsl, wdl, h, as_, ad_, N);
        aggregate<<<aggGrid, TPB, 0, stream>>>(xin, h, as_, ad_, col, rowptr,
                                               bl, gl, btl, xout, N);
        xin = xout;
    }
}